// Round 7
// baseline (640.079 us; speedup 1.0000x reference)
//
#include <hip/hip_runtime.h>

// ---------------------------------------------------------------------------
// DR_CRN_Multicause fused forward — round 7: 16 waves/block (4 waves/SIMD TLP)
//   nt-split + nt-paired tiles, A-operands from LDS, weights ~once per block.
//   B=131072, N_CONF=512, H1=513(->544), N_REP=256, HP=257(->288), N_TREAT=64
// out (FLOAT32): pred_sel[B] | log_prop[B*64] | mmd[1] | cause[B]
// LDS (138240 B): Cs[0,33792) | Os[33792,67584) | Hs[67584,138240)
//   Xs[64][520] overlays [0,66560) (alive stage -> end L1o; Cs flushed after)
//   headB/Hp overlay Hs region after L2o.
// Work split (16 waves): L1 17 pairs (1 extra); L2c/L2o 8 pairs x 2 row-halves
//   = 16 jobs exactly; propL1 9 pairs x 2 halves = 18 jobs (2 extra);
//   head 4 row-groups x 4 nt = 16; propL2/softmax/selection on waves 0-3.
// ---------------------------------------------------------------------------

typedef __attribute__((ext_vector_type(8))) short bf16x8;
typedef __attribute__((ext_vector_type(4))) float f32x4;
typedef __attribute__((ext_vector_type(4))) short s16x4;

#define MFMA16 __builtin_amdgcn_mfma_f32_16x16x32_bf16

__device__ __forceinline__ short f2bf(float f) {
  union { float f; unsigned u; } v; v.f = f;
  return (short)((v.u + 0x7FFFu + ((v.u >> 16) & 1u)) >> 16);  // RNE
}

// ---- prep: convert+pad all weights/biases into ws (single launch) ----------
__global__ void prep_weights(const float* __restrict__ W1c, const float* __restrict__ W2c,
                             const float* __restrict__ W1o, const float* __restrict__ W2o,
                             const float* __restrict__ W1p, const float* __restrict__ W2p,
                             const float* __restrict__ Wh,
                             const float* __restrict__ b1c, const float* __restrict__ b1o,
                             const float* __restrict__ b1p,
                             char* __restrict__ ws) {
  int s = blockIdx.x * 256 + threadIdx.x;
  if (s < 960512) {                      // bf16 weight region (shorts)
    float v;
    if (s < 278528)      { int n = s >> 9,        k = s & 511;        v = (n < 513) ? W1c[n * 512 + k] : 0.f; }
    else if (s < 417792) { int i = s - 278528; int n = i / 544, k = i - n * 544; v = (k < 513) ? W2c[n * 513 + k] : 0.f; }
    else if (s < 696320) { int i = s - 417792; int n = i >> 9,  k = i & 511;     v = (n < 513) ? W1o[n * 512 + k] : 0.f; }
    else if (s < 835584) { int i = s - 696320; int n = i / 544, k = i - n * 544; v = (k < 513) ? W2o[n * 513 + k] : 0.f; }
    else if (s < 909312) { int i = s - 835584; int n = i >> 8,  k = i & 255;     v = (n < 257) ? W1p[n * 256 + k] : 0.f; }
    else if (s < 927744) { int i = s - 909312; int n = i / 288, k = i - n * 288; v = (k < 257) ? W2p[n * 257 + k] : 0.f; }
    else                 { v = Wh[s - 927744]; }
    ((short*)ws)[s] = f2bf(v);
  } else if (s < 961888) {               // padded f32 biases
    int j = s - 960512;
    float v;
    if (j < 544)       v = (j < 513) ? b1c[j] : 0.f;
    else if (j < 1088) { int q = j - 544;  v = (q < 513) ? b1o[q] : 0.f; }
    else               { int q = j - 1088; v = (q < 257) ? b1p[q] : 0.f; }
    ((float*)(ws + 1921024))[j] = v;
  }
}

// paired 2x16-col tile over NRG row-groups starting at rg0:
// acc0 = cols [nt0*16,+16), acc1 = cols [nt0*16+16,+16).
template<int NKT, int NRG>
__device__ __forceinline__ void pair_mm(const short* __restrict__ W, int ldw,
                                        const short* __restrict__ A, int lda,
                                        int nt0, int rg0, int l15, int l4,
                                        f32x4 (&acc0)[NRG], f32x4 (&acc1)[NRG]) {
  bf16x8 b0[NKT], b1[NKT];
  const short* w0 = W + (nt0 * 16 + l15) * ldw + l4 * 8;
  const short* w1 = w0 + 16 * ldw;
  #pragma unroll
  for (int kt = 0; kt < NKT; ++kt) {
    b0[kt] = *(const bf16x8*)(w0 + kt * 32);
    b1[kt] = *(const bf16x8*)(w1 + kt * 32);
  }
  #pragma unroll
  for (int g = 0; g < NRG; ++g) {
    acc0[g] = (f32x4){0.f, 0.f, 0.f, 0.f};
    acc1[g] = (f32x4){0.f, 0.f, 0.f, 0.f};
  }
  #pragma unroll
  for (int kt = 0; kt < NKT; ++kt) {
    #pragma unroll
    for (int g = 0; g < NRG; ++g) {
      bf16x8 a = *(const bf16x8*)(A + ((rg0 + g) * 16 + l15) * lda + kt * 32 + l4 * 8);
      acc0[g] = MFMA16(a, b0[kt], acc0[g], 0, 0, 0);
      acc1[g] = MFMA16(a, b1[kt], acc1[g], 0, 0, 0);
    }
  }
}

template<int NRG>
__device__ __forceinline__ void store_tile(short* __restrict__ dst, int ldd, int nt,
                                           const float* __restrict__ bias,
                                           const f32x4 (&acc)[NRG], int rg0,
                                           int l15, int l4, bool relu) {
  float bi = bias[nt * 16 + l15];
  #pragma unroll
  for (int g = 0; g < NRG; ++g)
    #pragma unroll
    for (int r = 0; r < 4; ++r) {
      float v = acc[g][r] + bi;
      if (relu) v = fmaxf(v, 0.f);
      dst[((rg0 + g) * 16 + l4 * 4 + r) * ldd + nt * 16 + l15] = f2bf(v);
    }
}

__global__ __launch_bounds__(1024, 4)
void fused_main(const float* __restrict__ x, const int* __restrict__ cause,
                const char* __restrict__ ws,
                const float* __restrict__ b2c, const float* __restrict__ b2o,
                const float* __restrict__ b2p, const float* __restrict__ bh,
                float* __restrict__ out) {
  const short* W1cb = (const short*)(ws);
  const short* W2cb = (const short*)(ws + 557056);
  const short* W1ob = (const short*)(ws + 835584);
  const short* W2ob = (const short*)(ws + 1392640);
  const short* W1pb = (const short*)(ws + 1671168);
  const short* W2pb = (const short*)(ws + 1818624);
  const short* Whb  = (const short*)(ws + 1855488);
  const float* b1cp = (const float*)(ws + 1921024);
  const float* b1op = (const float*)(ws + 1923200);
  const float* b1pp = (const float*)(ws + 1925376);

  extern __shared__ __align__(16) char lds[];
  short* Cs    = (short*)lds;             // [64][264] (flushed after Xs dead)
  short* Os    = (short*)(lds + 33792);   // [64][264]
  short* Hs    = (short*)(lds + 67584);   // [64][552]
  short* Xs    = (short*)lds;             // [64][520] overlays Cs|Os
  float* headB = (float*)(lds + 67584);   // [64][68] f32 (after Hs dead)
  short* Hp    = (short*)(lds + 67584);   // [64][296]    (after headB dead)

  const int tid  = threadIdx.x;
  const int lane = tid & 63;
  const int wid  = tid >> 6;             // 0..15
  const int l15  = lane & 15;
  const int l4   = lane >> 4;            // 0..3
  const size_t grow0 = (size_t)blockIdx.x * 64;

  // ---- stage X (f32 -> bf16), nontemporal to keep weights resident in L2 --
  {
    const f32x4* xsrc = (const f32x4*)(x + grow0 * 512);
    for (int i = tid; i < 8192; i += 1024) {   // 64 rows * 128 float4
      f32x4 v = __builtin_nontemporal_load(xsrc + i);
      int r = i >> 7, c = i & 127;
      s16x4 p;
      p.x = f2bf(v.x); p.y = f2bf(v.y); p.z = f2bf(v.z); p.w = f2bf(v.w);
      *(s16x4*)&Xs[r * 520 + c * 4] = p;
    }
  }
  __syncthreads();   // B0: X staged

  // ---- L1c: Hs = relu(X @ W1c^T + b1c); 17 pairs, extra -> wave 0 ----
  for (int p = wid; p < 17; p += 16) {
    f32x4 a0[4], a1[4];
    pair_mm<16, 4>(W1cb, 512, Xs, 520, 2 * p, 0, l15, l4, a0, a1);
    store_tile<4>(Hs, 552, 2 * p,     b1cp, a0, 0, l15, l4, true);
    store_tile<4>(Hs, 552, 2 * p + 1, b1cp, a1, 0, l15, l4, true);
  }
  __syncthreads();   // B1: H_c complete

  // ---- L2c: crep = Hs @ W2c^T + b2c; 8 pairs x 2 row-halves = 16 jobs.
  //      Kept packed-bf16 in regs (Xs still alive). ----
  const int p2 = wid >> 1;        // pair 0..7
  const int h2 = (wid & 1) * 2;   // rg base 0 or 2
  s16x4 crp[2][2];                // [jj][g]: nt = 2*p2+jj, rg = h2+g
  {
    f32x4 a0[2], a1[2];
    pair_mm<17, 2>(W2cb, 544, Hs, 552, 2 * p2, h2, l15, l4, a0, a1);
    float bi0 = b2c[p2 * 32 + l15], bi1 = b2c[p2 * 32 + 16 + l15];
    #pragma unroll
    for (int g = 0; g < 2; ++g) {
      s16x4 q0, q1;
      #pragma unroll
      for (int r = 0; r < 4; ++r) {
        q0[r] = f2bf(a0[g][r] + bi0);
        q1[r] = f2bf(a1[g][r] + bi1);
      }
      crp[0][g] = q0; crp[1][g] = q1;
    }
  }
  __syncthreads();   // B2: Hs reads done -> L1o may overwrite

  // ---- L1o: Hs = relu(X @ W1o^T + b1o); extra pair -> wave 8 ----
  for (int p = (wid + 8) & 15; p < 17; p += 16) {
    f32x4 a0[4], a1[4];
    pair_mm<16, 4>(W1ob, 512, Xs, 520, 2 * p, 0, l15, l4, a0, a1);
    store_tile<4>(Hs, 552, 2 * p,     b1op, a0, 0, l15, l4, true);
    store_tile<4>(Hs, 552, 2 * p + 1, b1op, a1, 0, l15, l4, true);
  }
  __syncthreads();   // B3: H_o complete; Xs dead everywhere

  // ---- flush crep -> Cs (region0, now free) ----
  #pragma unroll
  for (int jj = 0; jj < 2; ++jj) {
    int nt = 2 * p2 + jj;
    #pragma unroll
    for (int g = 0; g < 2; ++g)
      #pragma unroll
      for (int r = 0; r < 4; ++r)
        Cs[((h2 + g) * 16 + l4 * 4 + r) * 264 + nt * 16 + l15] = crp[jj][g][r];
  }

  // ---- L2o: Os = Hs @ W2o^T + b2o; same 16-job split ----
  {
    f32x4 a0[2], a1[2];
    pair_mm<17, 2>(W2ob, 544, Hs, 552, 2 * p2, h2, l15, l4, a0, a1);
    store_tile<2>(Os, 264, 2 * p2,     b2o, a0, h2, l15, l4, false);
    store_tile<2>(Os, 264, 2 * p2 + 1, b2o, a1, h2, l15, l4, false);
  }
  __syncthreads();   // B4: Cs+Os complete; Hs dead

  // ---- head: wave = (row-group g, nt j); 4x4 = 16 waves ----
  {
    const int g  = wid >> 2;
    const int j  = wid & 3;
    const int rb = g * 16;
    bf16x8 acf[16];
    #pragma unroll
    for (int kt = 0; kt < 8; ++kt) {
      acf[kt]     = *(const bf16x8*)&Cs[(rb + l15) * 264 + kt * 32 + l4 * 8];
      acf[kt + 8] = *(const bf16x8*)&Os[(rb + l15) * 264 + kt * 32 + l4 * 8];
    }
    f32x4 hacc = {0.f, 0.f, 0.f, 0.f};
    const short* w0 = Whb + (j * 16 + l15) * 512 + l4 * 8;
    #pragma unroll
    for (int kt = 0; kt < 16; ++kt)
      hacc = MFMA16(acf[kt], *(const bf16x8*)(w0 + kt * 32), hacc, 0, 0, 0);
    // headB overlays Hs region (dead after B4)
    #pragma unroll
    for (int r = 0; r < 4; ++r)
      headB[(rb + l4 * 4 + r) * 68 + j * 16 + l15] = hacc[r];
  }
  __syncthreads();   // B5: headB complete

  // one-hot selection + cause passthrough: waves 0..3 handle 16 rows each
  if (wid < 4 && lane < 16) {
    int row = wid * 16 + lane;
    size_t gr = grow0 + row;
    int cv = cause[gr];
    out[gr] = headB[row * 68 + cv] + bh[cv];
    out[(size_t)8519681 + gr] = (float)cv;
  }
  __syncthreads();   // B6: selection reads done -> Hp may overwrite

  // ---- propensity L1: Hp = relu(Cs @ W1p^T + b1p);
  //      9 pairs x 2 halves = 18 jobs, extras -> waves 12,13 ----
  for (int q = (wid + 4) & 15; q < 18; q += 16) {
    int pp = q >> 1, hh = (q & 1) * 2;
    f32x4 a0[2], a1[2];
    pair_mm<8, 2>(W1pb, 256, Cs, 264, 2 * pp, hh, l15, l4, a0, a1);
    store_tile<2>(Hp, 296, 2 * pp,     b1pp, a0, hh, l15, l4, true);
    store_tile<2>(Hp, 296, 2 * pp + 1, b1pp, a1, hh, l15, l4, true);
  }
  __syncthreads();   // B7: Hp complete

  // ---- propensity L2 + log_softmax: waves 0..3, one 16-row group each ----
  if (wid < 4) {
    const int rb = wid * 16;
    f32x4 pl[4];
    {
      bf16x8 ahp[9];
      #pragma unroll
      for (int kt = 0; kt < 9; ++kt)
        ahp[kt] = *(const bf16x8*)&Hp[(rb + l15) * 296 + kt * 32 + l4 * 8];
      #pragma unroll
      for (int nt = 0; nt < 4; ++nt) {
        f32x4 a0 = {0.f, 0.f, 0.f, 0.f};
        const short* w0 = W2pb + (nt * 16 + l15) * 288 + l4 * 8;
        #pragma unroll
        for (int kt = 0; kt < 9; ++kt)
          a0 = MFMA16(ahp[kt], *(const bf16x8*)(w0 + kt * 32), a0, 0, 0, 0);
        float bi = b2p[nt * 16 + l15];
        #pragma unroll
        for (int r = 0; r < 4; ++r) a0[r] += bi;
        pl[nt] = a0;
      }
    }
    #pragma unroll
    for (int r = 0; r < 4; ++r) {
      float m = fmaxf(fmaxf(pl[0][r], pl[1][r]), fmaxf(pl[2][r], pl[3][r]));
      m = fmaxf(m, __shfl_xor(m, 1, 64));
      m = fmaxf(m, __shfl_xor(m, 2, 64));
      m = fmaxf(m, __shfl_xor(m, 4, 64));
      m = fmaxf(m, __shfl_xor(m, 8, 64));
      float s = __expf(pl[0][r] - m) + __expf(pl[1][r] - m)
              + __expf(pl[2][r] - m) + __expf(pl[3][r] - m);
      s += __shfl_xor(s, 1, 64);
      s += __shfl_xor(s, 2, 64);
      s += __shfl_xor(s, 4, 64);
      s += __shfl_xor(s, 8, 64);
      float lse = m + __logf(s);
      size_t gr = grow0 + rb + l4 * 4 + r;
      float* o1 = out + 131072 + gr * 64;
      #pragma unroll
      for (int nt = 0; nt < 4; ++nt)
        o1[nt * 16 + l15] = pl[nt][r] - lse;
    }
  }
  if (blockIdx.x == 0 && tid == 0) out[8519680] = 0.0f;   // mmd
}

extern "C" void kernel_launch(void* const* d_in, const int* in_sizes, int n_in,
                              void* d_out, int out_size, void* d_ws, size_t ws_size,
                              hipStream_t stream) {
  (void)in_sizes; (void)n_in; (void)out_size; (void)ws_size;
  const float* x    = (const float*)d_in[0];
  const int*   cause= (const int*)  d_in[1];
  const float* W1c  = (const float*)d_in[2];
  const float* b1c  = (const float*)d_in[3];
  const float* W2c  = (const float*)d_in[4];
  const float* b2c  = (const float*)d_in[5];
  const float* W1o  = (const float*)d_in[6];
  const float* b1o  = (const float*)d_in[7];
  const float* W2o  = (const float*)d_in[8];
  const float* b2o  = (const float*)d_in[9];
  const float* W1p  = (const float*)d_in[10];
  const float* b1p  = (const float*)d_in[11];
  const float* W2p  = (const float*)d_in[12];
  const float* b2p  = (const float*)d_in[13];
  const float* Wh   = (const float*)d_in[14];
  const float* bh   = (const float*)d_in[15];
  char* ws = (char*)d_ws;

  prep_weights<<<3758, 256, 0, stream>>>(W1c, W2c, W1o, W2o, W1p, W2p, Wh,
                                         b1c, b1o, b1p, ws);

  (void)hipFuncSetAttribute((const void*)fused_main,
                            hipFuncAttributeMaxDynamicSharedMemorySize, 138240);
  fused_main<<<2048, 1024, 138240, stream>>>(x, cause, ws, b2c, b2o, b2p, bh,
                                             (float*)d_out);
}